// Round 1
// baseline (86.906 us; speedup 1.0000x reference)
//
#include <hip/hip_runtime.h>
#include <math.h>

// DNFLayer: B=32, N=32, P0=16, P1=32, P2=16, R=3, D=8, V=2
// P = N*(N-1) = 992 perms, num_in = 112, out stride per batch = 16912.
#define NIN 112
#define NM1 31
#define OUTSTRIDE 16912
#define XSTRIDE 116   // padded row stride for x in LDS (20*jj mod 32 distinct -> conflict-free)

// Block = (b, i): 1024 blocks x 256 threads.
// Thread t: jj = t>>3 (perm column, 0..30 valid), d = t&7 (disjunct slot).
// Each thread computes conjuncts c[r] for its (jj,d) as a product over 112 features,
// with per-feature affine term x*s + t derived from softmax(and_kernel).
__global__ __launch_bounds__(256) void dnf_main(
    const float* __restrict__ nullary, const float* __restrict__ unary,
    const float* __restrict__ binary, const float* __restrict__ andk,
    const float* __restrict__ ork, float* __restrict__ out,
    float* __restrict__ pp)
{
    __shared__ __align__(16) float2 st[NIN * 24];     // [f][rd], rd = r*8+d
    __shared__ __align__(16) float  xl[32 * XSTRIDE]; // [jj][f] padded (row 31 unused/garbage-safe)
    __shared__ float okl[24];
    __shared__ float a0[NM1], a1[NM1], r2[NM1];
    __shared__ float urule;

    const int t = threadIdx.x;
    const int b = blockIdx.x >> 5;
    const int i = blockIdx.x & 31;

    // --- softmax prep: and_kernel (3,8,112,3) -> slope/intercept table ---
    for (int idx = t; idx < NIN * 24; idx += 256) {
        // idx = rd*112 + f
        float w0 = andk[idx * 3 + 0], w1 = andk[idx * 3 + 1], w2 = andk[idx * 3 + 2];
        float m  = fmaxf(w0, fmaxf(w1, w2));
        float e0 = __expf(w0 - m), e1 = __expf(w1 - m), e2 = __expf(w2 - m);
        float inv = 1.0f / (e0 + e1 + e2);
        int rd = idx / NIN, f = idx - rd * NIN;
        st[f * 24 + rd] = make_float2((e0 - e1) * inv, (e1 + e2) * inv);
    }
    if (t < 24) okl[t] = 1.0f / (1.0f + __expf(-ork[t]));

    // --- stage x[jj][0..111] = [null16 | unary_i32 | unary_j32 | bin_ij16 | bin_ji16] ---
    for (int idx = t; idx < NM1 * NIN; idx += 256) {
        int jj = idx / NIN, col = idx - jj * NIN;
        int j = jj + (jj >= i);
        float v;
        if (col < 16)      v = nullary[b * 16 + col];
        else if (col < 48) v = unary[(b * 32 + i) * 32 + (col - 16)];
        else if (col < 80) v = unary[(b * 32 + j) * 32 + (col - 48)];
        else if (col < 96) v = binary[((b * 32 + i) * 31 + jj) * 16 + (col - 80)];
        else {
            int i2 = (jj < i) ? (i - 1) : i;
            v = binary[((b * 32 + j) * 31 + i2) * 16 + (col - 96)];
        }
        xl[jj * XSTRIDE + col] = v;
    }
    __syncthreads();

    const int jj = t >> 3;
    const int d  = t & 7;

    // --- conjunct products: 2 interleaved chains per r to cut dependency latency ---
    float pA0 = 1.f, pA1 = 1.f, pA2 = 1.f;
    float pB0 = 1.f, pB1 = 1.f, pB2 = 1.f;
    const float* xrow = &xl[jj * XSTRIDE];
    for (int f = 0; f < NIN; f += 4) {
        float4 xq = *(const float4*)(xrow + f);
#pragma unroll
        for (int k = 0; k < 4; ++k) {
            float xv = (k == 0) ? xq.x : (k == 1) ? xq.y : (k == 2) ? xq.z : xq.w;
            const float2* sp = &st[(f + k) * 24 + d];
            float2 c0 = sp[0], c1 = sp[8], c2 = sp[16];
            if (k & 1) {
                pB0 *= fmaf(xv, c0.x, c0.y);
                pB1 *= fmaf(xv, c1.x, c1.y);
                pB2 *= fmaf(xv, c2.x, c2.y);
            } else {
                pA0 *= fmaf(xv, c0.x, c0.y);
                pA1 *= fmaf(xv, c1.x, c1.y);
                pA2 *= fmaf(xv, c2.x, c2.y);
            }
        }
    }

    // v[r] = 1 - c[r]*ok[rd]; product over d (8 lanes, aligned groups) = 1 - disjunct
    float v0, v1, v2;
    {
        float c0 = pA0 * pB0, c1 = pA1 * pB1, c2 = pA2 * pB2;
        v0 = 1.0f - c0 * okl[d];
        v1 = 1.0f - c1 * okl[8 + d];
        v2 = 1.0f - c2 * okl[16 + d];
    }
#pragma unroll
    for (int m = 1; m < 8; m <<= 1) {
        v0 *= __shfl_xor(v0, m);
        v1 *= __shfl_xor(v1, m);
        v2 *= __shfl_xor(v2, m);
    }
    if (d == 0 && jj < NM1) {
        a0[jj] = v0;             // (1 - rule0) for this (b,i,jj)
        a1[jj] = v1;             // (1 - rule1)
        r2[jj] = 1.0f - v2;      // rule2
    }
    __syncthreads();

    if (t == 0) {
        float P0 = 1.f, P1 = 1.f;
        for (int k = 0; k < NM1; ++k) { P0 *= a0[k]; P1 *= a1[k]; }
        pp[b * 32 + i] = P0;     // partial nullary product for (b,i)
        urule = 1.0f - P1;       // unary rule for (b,i)
    }
    __syncthreads();

    // --- unary output: 32 channels, channel 31 merged ---
    if (t < 32) {
        float old = unary[(b * 32 + i) * 32 + t];
        float val = (t == 31) ? 1.0f - (1.0f - old) * (1.0f - urule) : old;
        out[b * OUTSTRIDE + 16 + i * 32 + t] = val;
    }
    // --- binary output: 31*16 values, channel 15 merged with rule2 ---
    for (int idx = t; idx < NM1 * 16; idx += 256) {
        int jj2 = idx >> 4, c = idx & 15;
        float old = binary[((b * 32 + i) * 31 + jj2) * 16 + c];
        float val = old;
        if (c == 15) val = 1.0f - (1.0f - old) * (1.0f - r2[jj2]);
        out[b * OUTSTRIDE + 16 + 1024 + (i * 31 + jj2) * 16 + c] = val;
    }
}

// Finalize: nullary probsum across all i per batch + nullary output (16 channels).
__global__ __launch_bounds__(1024) void dnf_final(
    const float* __restrict__ nullary, const float* __restrict__ pp,
    float* __restrict__ out)
{
    int t = threadIdx.x;
    int b = t >> 5, s = t & 31;
    float v = pp[b * 32 + s];
#pragma unroll
    for (int m = 1; m < 32; m <<= 1) v *= __shfl_xor(v, m);  // masks <32 stay in 32-lane half
    if (s < 16) {
        float old = nullary[b * 16 + s];
        // merged = 1 - (1-old)*(1-rule0), rule0 = 1 - v  =>  1 - (1-old)*v
        float val = (s == 15) ? 1.0f - (1.0f - old) * v : old;
        out[b * OUTSTRIDE + s] = val;
    }
}

extern "C" void kernel_launch(void* const* d_in, const int* in_sizes, int n_in,
                              void* d_out, int out_size, void* d_ws, size_t ws_size,
                              hipStream_t stream) {
    const float* nullary = (const float*)d_in[0];
    const float* unary   = (const float*)d_in[1];
    const float* binary  = (const float*)d_in[2];
    const float* andk    = (const float*)d_in[3];
    const float* ork     = (const float*)d_in[4];
    float* out = (float*)d_out;
    float* pp  = (float*)d_ws;   // 1024 floats of scratch

    dnf_main<<<dim3(1024), dim3(256), 0, stream>>>(nullary, unary, binary, andk, ork, out, pp);
    dnf_final<<<dim3(1), dim3(1024), 0, stream>>>(nullary, pp, out);
}

// Round 2
// 81.981 us; speedup vs baseline: 1.0601x; 1.0601x over previous
//
#include <hip/hip_runtime.h>
#include <math.h>

// DNFLayer: B=32, N=32, P0=16, P1=32, P2=16, R=3, D=8, V=2
// P = N*(N-1) = 992 perms, num_in = 112, out stride per batch = 16912.
#define NIN 112
#define NM1 31
#define OUTSTRIDE 16912
#define XSTRIDE 116   // padded x row stride: (116*jj+f) mod 32 = (20jj+f), jj mod 8 distinct -> conflict-free b128

typedef float v2f __attribute__((ext_vector_type(2)));

// Block = (b, i): 1024 blocks x 256 threads. Thread t: jj = t>>3, d = t&7.
// term(x; r) = x*s_r + t_r with (s,t) from softmax(and_kernel).
// Rules 0,1 computed as packed float2 (v_pk_fma_f32), rule 2 scalar.
__global__ __launch_bounds__(256) void dnf_main(
    const float* __restrict__ nullary, const float* __restrict__ unary,
    const float* __restrict__ binary, const float* __restrict__ andk,
    const float* __restrict__ ork, float* __restrict__ out,
    float* __restrict__ pp)
{
    __shared__ __align__(16) float4 stAB[NIN * 8];    // [f*8+d] = (s0,s1,t0,t1)  16B stride: conflict-free
    __shared__ __align__(16) float2 stC [NIN * 8];    // [f*8+d] = (s2,t2)         8B stride: 2-way (free)
    __shared__ __align__(16) float  xl[32 * XSTRIDE]; // [jj][f]
    __shared__ float okl[24];
    __shared__ float a0[NM1], a1[NM1], r2s[NM1];
    __shared__ float urule;

    const int t = threadIdx.x;
    const int b = blockIdx.x >> 5;
    const int i = blockIdx.x & 31;

    // --- softmax prep: 896 (f,d) records, 3 rules each ---
    for (int idx = t; idx < NIN * 8; idx += 256) {
        int f = idx >> 3, d = idx & 7;
        float s[3], tt[3];
#pragma unroll
        for (int r = 0; r < 3; ++r) {
            int base = ((r * 8 + d) * NIN + f) * 3;
            float w0 = andk[base], w1 = andk[base + 1], w2 = andk[base + 2];
            float m  = fmaxf(w0, fmaxf(w1, w2));
            float e0 = __expf(w0 - m), e1 = __expf(w1 - m), e2 = __expf(w2 - m);
            float inv = 1.0f / (e0 + e1 + e2);
            s[r] = (e0 - e1) * inv; tt[r] = (e1 + e2) * inv;
        }
        stAB[idx] = make_float4(s[0], s[1], tt[0], tt[1]);
        stC [idx] = make_float2(s[2], tt[2]);
    }
    if (t < 24) okl[t] = 1.0f / (1.0f + __expf(-ork[t]));

    // --- stage x[jj][0..111] = [null16 | unary_i32 | unary_j32 | bin_ij16 | bin_ji16] ---
    for (int idx = t; idx < NM1 * NIN; idx += 256) {
        int jj = idx / NIN, col = idx - jj * NIN;
        int j = jj + (jj >= i);
        float v;
        if (col < 16)      v = nullary[b * 16 + col];
        else if (col < 48) v = unary[(b * 32 + i) * 32 + (col - 16)];
        else if (col < 80) v = unary[(b * 32 + j) * 32 + (col - 48)];
        else if (col < 96) v = binary[((b * 32 + i) * 31 + jj) * 16 + (col - 80)];
        else {
            int i2 = (jj < i) ? (i - 1) : i;
            v = binary[((b * 32 + j) * 31 + i2) * 16 + (col - 96)];
        }
        xl[jj * XSTRIDE + col] = v;
    }
    __syncthreads();

    const int jj = t >> 3;
    const int d  = t & 7;

    // --- conjunct products: rules 0/1 packed, rule 2 scalar; 2 interleaved chains each ---
    v2f pA01 = {1.f, 1.f}, pB01 = {1.f, 1.f};
    float pA2 = 1.f, pB2 = 1.f;
    const float4* xrow = (const float4*)&xl[jj * XSTRIDE];
    const float4* pab  = &stAB[d];
    const float2* pc   = &stC[d];
#pragma unroll
    for (int f4 = 0; f4 < NIN / 4; ++f4) {
        float4 xq = xrow[f4];
#pragma unroll
        for (int k = 0; k < 4; ++k) {
            float xv = (k == 0) ? xq.x : (k == 1) ? xq.y : (k == 2) ? xq.z : xq.w;
            int fo = (f4 * 4 + k) * 8;           // compile-time after unroll -> imm offsets
            float4 ab = pab[fo];
            float2 c  = pc[fo];
            v2f xx = {xv, xv};
            v2f term01 = xx * (v2f){ab.x, ab.y} + (v2f){ab.z, ab.w};
            float term2 = fmaf(xv, c.x, c.y);
            if (k & 1) { pB01 *= term01; pB2 *= term2; }
            else       { pA01 *= term01; pA2 *= term2; }
        }
    }

    // v[r] = 1 - c[r]*ok[rd]; product over d (8-lane aligned groups) = 1 - disjunct
    v2f c01 = pA01 * pB01;
    float c2 = pA2 * pB2;
    float v0 = 1.0f - c01.x * okl[d];
    float v1 = 1.0f - c01.y * okl[8 + d];
    float v2 = 1.0f - c2   * okl[16 + d];
#pragma unroll
    for (int m = 1; m < 8; m <<= 1) {
        v0 *= __shfl_xor(v0, m);
        v1 *= __shfl_xor(v1, m);
        v2 *= __shfl_xor(v2, m);
    }
    if (d == 0 && jj < NM1) {
        a0[jj] = v0;             // (1 - rule0) for this (b,i,jj)
        a1[jj] = v1;             // (1 - rule1)
        r2s[jj] = 1.0f - v2;     // rule2
    }
    __syncthreads();

    // --- products over jj (wave 0, shuffle reduce over 32 lanes) ---
    if (t < 32) {
        float q0 = (t < NM1) ? a0[t] : 1.0f;
        float q1 = (t < NM1) ? a1[t] : 1.0f;
#pragma unroll
        for (int m = 1; m < 32; m <<= 1) {
            q0 *= __shfl_xor(q0, m);
            q1 *= __shfl_xor(q1, m);
        }
        if (t == 0) {
            pp[b * 32 + i] = q0;     // partial nullary product for (b,i)
            urule = 1.0f - q1;       // unary rule for (b,i)
        }
    }
    __syncthreads();

    // --- unary output: 32 channels, channel 31 merged (old values from LDS row 0) ---
    if (t < 32) {
        float old = xl[16 + t];
        float val = (t == 31) ? 1.0f - (1.0f - old) * (1.0f - urule) : old;
        out[b * OUTSTRIDE + 16 + i * 32 + t] = val;
    }
    // --- binary output: 31*16 values, channel 15 merged with rule2 ---
    for (int idx = t; idx < NM1 * 16; idx += 256) {
        int jj2 = idx >> 4, c = idx & 15;
        float old = xl[jj2 * XSTRIDE + 80 + c];
        float val = old;
        if (c == 15) val = 1.0f - (1.0f - old) * (1.0f - r2s[jj2]);
        out[b * OUTSTRIDE + 16 + 1024 + (i * 31 + jj2) * 16 + c] = val;
    }
}

// Finalize: nullary probsum across all i per batch + nullary output (16 channels).
__global__ __launch_bounds__(1024) void dnf_final(
    const float* __restrict__ nullary, const float* __restrict__ pp,
    float* __restrict__ out)
{
    int t = threadIdx.x;
    int b = t >> 5, s = t & 31;
    float v = pp[b * 32 + s];
#pragma unroll
    for (int m = 1; m < 32; m <<= 1) v *= __shfl_xor(v, m);  // masks <32 stay in 32-lane half
    if (s < 16) {
        float old = nullary[b * 16 + s];
        // merged = 1 - (1-old)*(1-rule0), rule0 = 1 - v  =>  1 - (1-old)*v
        float val = (s == 15) ? 1.0f - (1.0f - old) * v : old;
        out[b * OUTSTRIDE + s] = val;
    }
}

extern "C" void kernel_launch(void* const* d_in, const int* in_sizes, int n_in,
                              void* d_out, int out_size, void* d_ws, size_t ws_size,
                              hipStream_t stream) {
    const float* nullary = (const float*)d_in[0];
    const float* unary   = (const float*)d_in[1];
    const float* binary  = (const float*)d_in[2];
    const float* andk    = (const float*)d_in[3];
    const float* ork     = (const float*)d_in[4];
    float* out = (float*)d_out;
    float* pp  = (float*)d_ws;   // 1024 floats of scratch

    dnf_main<<<dim3(1024), dim3(256), 0, stream>>>(nullary, unary, binary, andk, ork, out, pp);
    dnf_final<<<dim3(1), dim3(1024), 0, stream>>>(nullary, pp, out);
}